// Round 1
// baseline (5499.030 us; speedup 1.0000x reference)
//
#include <hip/hip_runtime.h>
#include <hip/hip_bf16.h>
#include <cstdint>

#define BATCH 64
#define SEQ   512
#define DIM   512
#define MTOT  (BATCH*SEQ)   // 32768

// ---------------------------------------------------------------------------
// Kernel 0: transpose W_hh [H][J] -> WT [J][H]  (so rnn_scan loads coalesce)
// ---------------------------------------------------------------------------
__global__ __launch_bounds__(256) void transpose512(const float* __restrict__ in,
                                                    float* __restrict__ out) {
    __shared__ float tile[32][33];
    const int bx = blockIdx.x * 32;   // j-block (output row block)
    const int by = blockIdx.y * 32;   // h-block (input row block)
    const int tx = threadIdx.x & 31;
    const int ty = threadIdx.x >> 5;  // 0..7
#pragma unroll
    for (int i = 0; i < 32; i += 8) {
        tile[ty + i][tx] = in[(size_t)(by + ty + i) * DIM + bx + tx];
    }
    __syncthreads();
#pragma unroll
    for (int i = 0; i < 32; i += 8) {
        out[(size_t)(bx + ty + i) * DIM + by + tx] = tile[tx][ty + i];
    }
}

// ---------------------------------------------------------------------------
// Kernel 1: fused embedding gather + input projection (NT GEMM, fp32)
//   xp[m][n] = sum_k emb[x[m]][k] * W_ih[n][k]  + b_ih[n] + b_hh[n]
//   m = b*SEQ + t   (so xp layout is [B][T][H])
// 64x64 tile, K-tile 64, 256 threads, 4x4 micro-tile / thread.
// ---------------------------------------------------------------------------
__global__ __launch_bounds__(256) void embed_proj(
    const int*   __restrict__ xidx,
    const float* __restrict__ emb,
    const float* __restrict__ W_ih,
    const float* __restrict__ b_ih,
    const float* __restrict__ b_hh,
    float*       __restrict__ xp) {
    __shared__ float As[64][68];  // As[k][m] (transposed in LDS)
    __shared__ float Bs[64][68];  // Bs[k][n]

    const int m0  = blockIdx.x * 64;
    const int n0  = blockIdx.y * 64;
    const int tid = threadIdx.x;

    const int lr = tid >> 4;          // 0..15 : row group for staging
    const int lc = (tid & 15) << 2;   // 0..60 : k offset for staging (float4)

    int rows[4];
#pragma unroll
    for (int i = 0; i < 4; i++) rows[i] = xidx[m0 + lr + 16 * i];

    const int tm = (tid & 15) << 2;   // output m offset 0..60
    const int tn = (tid >> 4) << 2;   // output n offset 0..60

    float acc[4][4];
#pragma unroll
    for (int i = 0; i < 4; i++)
#pragma unroll
        for (int j = 0; j < 4; j++) acc[i][j] = 0.0f;

    for (int k0 = 0; k0 < DIM; k0 += 64) {
#pragma unroll
        for (int i = 0; i < 4; i++) {
            const int rl = lr + 16 * i;
            const float4 a = *(const float4*)&emb[(size_t)rows[i] * DIM + k0 + lc];
            As[lc + 0][rl] = a.x; As[lc + 1][rl] = a.y;
            As[lc + 2][rl] = a.z; As[lc + 3][rl] = a.w;
            const float4 b = *(const float4*)&W_ih[(size_t)(n0 + rl) * DIM + k0 + lc];
            Bs[lc + 0][rl] = b.x; Bs[lc + 1][rl] = b.y;
            Bs[lc + 2][rl] = b.z; Bs[lc + 3][rl] = b.w;
        }
        __syncthreads();
#pragma unroll 8
        for (int kk = 0; kk < 64; kk++) {
            const float4 a = *(const float4*)&As[kk][tm];
            const float4 b = *(const float4*)&Bs[kk][tn];
            acc[0][0] = fmaf(a.x, b.x, acc[0][0]);
            acc[0][1] = fmaf(a.x, b.y, acc[0][1]);
            acc[0][2] = fmaf(a.x, b.z, acc[0][2]);
            acc[0][3] = fmaf(a.x, b.w, acc[0][3]);
            acc[1][0] = fmaf(a.y, b.x, acc[1][0]);
            acc[1][1] = fmaf(a.y, b.y, acc[1][1]);
            acc[1][2] = fmaf(a.y, b.z, acc[1][2]);
            acc[1][3] = fmaf(a.y, b.w, acc[1][3]);
            acc[2][0] = fmaf(a.z, b.x, acc[2][0]);
            acc[2][1] = fmaf(a.z, b.y, acc[2][1]);
            acc[2][2] = fmaf(a.z, b.z, acc[2][2]);
            acc[2][3] = fmaf(a.z, b.w, acc[2][3]);
            acc[3][0] = fmaf(a.w, b.x, acc[3][0]);
            acc[3][1] = fmaf(a.w, b.y, acc[3][1]);
            acc[3][2] = fmaf(a.w, b.z, acc[3][2]);
            acc[3][3] = fmaf(a.w, b.w, acc[3][3]);
        }
        __syncthreads();
    }

    const int n = n0 + tn;
    const float bias0 = b_ih[n + 0] + b_hh[n + 0];
    const float bias1 = b_ih[n + 1] + b_hh[n + 1];
    const float bias2 = b_ih[n + 2] + b_hh[n + 2];
    const float bias3 = b_ih[n + 3] + b_hh[n + 3];
#pragma unroll
    for (int i = 0; i < 4; i++) {
        float4 o;
        o.x = acc[i][0] + bias0;
        o.y = acc[i][1] + bias1;
        o.z = acc[i][2] + bias2;
        o.w = acc[i][3] + bias3;
        *(float4*)&xp[(size_t)(m0 + tm + i) * DIM + n] = o;
    }
}

// ---------------------------------------------------------------------------
// Kernel 2: sequential RNN scan.
//  32 workgroups x 512 threads; wg handles batch rows b0=2*blk, b0+1.
//  thread owns column h' = tid for both rows. W_hh streamed (transposed) from
//  L2 each step; h vectors live in LDS (broadcast reads).
//  In-place: buf holds xp on input, h_t on output (read-before-write / thread).
// ---------------------------------------------------------------------------
__global__ __launch_bounds__(512) void rnn_scan(const float* __restrict__ WT,
                                                float* __restrict__ buf) {
    __shared__ float h0s[DIM];
    __shared__ float h1s[DIM];
    const int tid = threadIdx.x;
    const int b0  = blockIdx.x * 2;

    h0s[tid] = 0.0f;
    h1s[tid] = 0.0f;
    __syncthreads();

    float* row0 = buf + (size_t)b0 * SEQ * DIM;
    float* row1 = buf + (size_t)(b0 + 1) * SEQ * DIM;

    for (int t = 0; t < SEQ; t++) {
        const int off = t * DIM + tid;
        // 4 partial accumulator pairs (x: row b0, y: row b0+1)
        float2 acc[4];
        acc[0].x = row0[off];
        acc[0].y = row1[off];
        acc[1].x = 0.f; acc[1].y = 0.f;
        acc[2].x = 0.f; acc[2].y = 0.f;
        acc[3].x = 0.f; acc[3].y = 0.f;

#pragma unroll 2
        for (int j = 0; j < DIM; j += 8) {
#pragma unroll
            for (int u = 0; u < 8; u++) {
                const float w  = WT[(size_t)(j + u) * DIM + tid];
                const float ha = h0s[j + u];
                const float hb = h1s[j + u];
                acc[u & 3].x = fmaf(ha, w, acc[u & 3].x);
                acc[u & 3].y = fmaf(hb, w, acc[u & 3].y);
            }
        }
        const float pre0 = (acc[0].x + acc[1].x) + (acc[2].x + acc[3].x);
        const float pre1 = (acc[0].y + acc[1].y) + (acc[2].y + acc[3].y);
        const float hn0 = tanhf(pre0);
        const float hn1 = tanhf(pre1);

        __syncthreads();          // all reads of h done before overwrite
        h0s[tid] = hn0;
        h1s[tid] = hn1;
        row0[off] = hn0;          // hid[b][t][h'] (same element we read as xp)
        row1[off] = hn1;
        __syncthreads();          // h visible before next step's reads
    }
}

// ---------------------------------------------------------------------------
// Kernel 3: softmax over H (per b,t) + transpose [B][T][H] -> out [B][H][T]
//  grid (B, T/64); each wg: 64 t-rows.
// ---------------------------------------------------------------------------
__global__ __launch_bounds__(256) void softmax_T(const float* __restrict__ hid,
                                                 float* __restrict__ out) {
    __shared__ float rowmax[64];
    __shared__ float rowinv[64];
    __shared__ float tile[64][65];

    const int b   = blockIdx.x;
    const int t0  = blockIdx.y * 64;
    const int tid = threadIdx.x;
    const float* base = hid + ((size_t)b * SEQ + t0) * DIM;

    // pass 1: per-row max and sum(exp) — 4 threads per row
    const int r = tid >> 2;   // 0..63 (t row)
    const int p = tid & 3;    // quad lane

    float m = -1e30f;
#pragma unroll 4
    for (int k = 0; k < 32; k++) {
        const float4 v = *(const float4*)&base[r * DIM + ((k * 4 + p) << 2)];
        m = fmaxf(m, fmaxf(fmaxf(v.x, v.y), fmaxf(v.z, v.w)));
    }
    m = fmaxf(m, __shfl_xor(m, 1));
    m = fmaxf(m, __shfl_xor(m, 2));

    float s = 0.0f;
#pragma unroll 4
    for (int k = 0; k < 32; k++) {
        const float4 v = *(const float4*)&base[r * DIM + ((k * 4 + p) << 2)];
        s += expf(v.x - m) + expf(v.y - m) + expf(v.z - m) + expf(v.w - m);
    }
    s += __shfl_xor(s, 1);
    s += __shfl_xor(s, 2);
    if (p == 0) {
        rowmax[r] = m;
        rowinv[r] = 1.0f / s;
    }
    __syncthreads();

    // pass 2: normalize + transposed store, 64(h)-wide chunks
    for (int hc = 0; hc < 8; hc++) {
#pragma unroll
        for (int i = 0; i < 16; i++) {
            const int lin = tid + 256 * i;   // 0..4095
            const int rr  = lin >> 6;        // t row 0..63
            const int cc  = lin & 63;        // h within chunk
            const float v = base[rr * DIM + hc * 64 + cc];
            tile[cc][rr] = expf(v - rowmax[rr]) * rowinv[rr];
        }
        __syncthreads();
#pragma unroll
        for (int i = 0; i < 16; i++) {
            const int lin = tid + 256 * i;
            const int hh  = lin >> 6;        // h local
            const int tt  = lin & 63;        // t local
            out[((size_t)b * DIM + hc * 64 + hh) * SEQ + t0 + tt] = tile[hh][tt];
        }
        __syncthreads();
    }
}

// ---------------------------------------------------------------------------
extern "C" void kernel_launch(void* const* d_in, const int* in_sizes, int n_in,
                              void* d_out, int out_size, void* d_ws, size_t ws_size,
                              hipStream_t stream) {
    const int*   x    = (const int*)  d_in[0];
    const float* emb  = (const float*)d_in[1];
    const float* W_ih = (const float*)d_in[2];
    const float* W_hh = (const float*)d_in[3];
    const float* b_ih = (const float*)d_in[4];
    const float* b_hh = (const float*)d_in[5];
    float* out = (float*)d_out;

    // 64 MB scratch: xp (then hid, in place) as [B][T][H]
    float* buf = (float*)d_ws;
    // W_hh^T staged in d_out (262144 floats << out_size); overwritten by
    // softmax_T after rnn_scan has consumed it (stream-ordered).
    float* WT = out;

    transpose512<<<dim3(16, 16), 256, 0, stream>>>(W_hh, WT);
    embed_proj<<<dim3(MTOT / 64, DIM / 64), 256, 0, stream>>>(x, emb, W_ih, b_ih, b_hh, buf);
    rnn_scan<<<32, 512, 0, stream>>>(WT, buf);
    softmax_T<<<dim3(BATCH, SEQ / 64), 256, 0, stream>>>(buf, out);
}